// Round 1
// baseline (679.153 us; speedup 1.0000x reference)
//
#include <hip/hip_runtime.h>
#include <math.h>

constexpr int EE = 128;    // embedding dim
constexpr int NS = 1024;   // spatial S
constexpr int NB = 32;     // batch
constexpr size_t BSE = (size_t)NB * NS * EE;  // 4194304 elems per (b,s,e) array

typedef __attribute__((ext_vector_type(4))) float f32x4;
typedef __attribute__((ext_vector_type(8))) short s16x8;
typedef __attribute__((ext_vector_type(4))) short s16x4;
typedef __attribute__((ext_vector_type(8))) __bf16 bf16v8;

__device__ __forceinline__ f32x4 mfma16(s16x8 a, s16x8 b, f32x4 c) {
  return __builtin_amdgcn_mfma_f32_16x16x32_bf16(
      __builtin_bit_cast(bf16v8, a), __builtin_bit_cast(bf16v8, b), c, 0, 0, 0);
}

__device__ __forceinline__ unsigned short f2bf(float f) {
  unsigned u = __builtin_bit_cast(unsigned, f);
  u += 0x7FFFu + ((u >> 16) & 1u);
  return (unsigned short)(u >> 16);
}
__device__ __forceinline__ float bf2f(unsigned short h) {
  unsigned u = ((unsigned)h) << 16;
  return __builtin_bit_cast(float, u);
}

// ---------------- workspace layout (bytes) ----------------
constexpr size_t EMB_OFF   = 0;                                   // 12 bf16 arrays [p][side][b*S+s][e]
constexpr size_t UNP_OFF   = EMB_OFF + 12ull * BSE * 2;           // f32 [3][B][S]
constexpr size_t SUMS_OFF  = UNP_OFF + 3ull * NB * NS * 4;        // f32 [6][S][S]
constexpr size_t SUMS2_OFF = SUMS_OFF + 6ull * NS * NS * 4;       // f32 [6][S][S]
constexpr size_t RB_OFF    = SUMS2_OFF + 6ull * NS * NS * 4;      // bf16 [6][S][S]
constexpr size_t CX_OFF    = RB_OFF + 6ull * NS * NS * 2;         // f32 [6][S]
constexpr size_t POTX_OFF  = CX_OFF + 6ull * NS * 4;              // f32 [6][B][S]
constexpr size_t POTY_OFF  = POTX_OFF + 6ull * NB * NS * 4;       // f32 [6][B][S]  (zeroed)
constexpr size_t CY_OFF    = POTY_OFF + 6ull * NB * NS * 4;       // f32 [6][S]     (zeroed)

// ================= embed kernel =================
// job = u*5 + m;  m: 0=unary, 1=sp_x, 2=sp_y, 3/4 = pair-side embeds of util u.
// Block: 64 positions x 128 outputs, K=128, 4 waves (2 pos-halves x 2 out-halves).
__global__ __launch_bounds__(256, 2) void embed_kernel(
    const float* __restrict__ utils,
    const float* __restrict__ un_w1, const float* __restrict__ un_b1,
    const float* __restrict__ un_w2, const float* __restrict__ un_b2,
    const float* __restrict__ sp_wx, const float* __restrict__ sp_bx,
    const float* __restrict__ sp_wy, const float* __restrict__ sp_by,
    const float* __restrict__ pw_wx, const float* __restrict__ pw_bx,
    const float* __restrict__ pw_wy, const float* __restrict__ pw_by,
    unsigned short* __restrict__ emb, float* __restrict__ unp)
{
  const int job = blockIdx.x >> 9;
  const int pt  = blockIdx.x & 511;
  const int u = job / 5, m = job % 5;

  const float* W; const float* bias;
  unsigned short* dst = nullptr;
  int mode;
  if (m == 0)      { W = un_w1 + u*EE*EE; bias = un_b1 + u*EE; mode = 0; }
  else if (m == 1) { W = sp_wx + u*EE*EE; bias = sp_bx + u*EE; dst = emb + (size_t)(2*u)*BSE;   mode = 1; }
  else if (m == 2) { W = sp_wy + u*EE*EE; bias = sp_by + u*EE; dst = emb + (size_t)(2*u+1)*BSE; mode = 1; }
  else {
    int q, side;
    if (u == 0)      { q = (m == 3) ? 0 : 1; side = 0; }
    else if (u == 1) { if (m == 3) { q = 0; side = 1; } else { q = 2; side = 0; } }
    else             { q = (m == 3) ? 1 : 2; side = 1; }
    W    = (side == 0 ? pw_wx : pw_wy) + q*EE*EE;
    bias = (side == 0 ? pw_bx : pw_by) + q*EE;
    dst  = emb + (size_t)(2*(3+q)+side)*BSE;
    mode = 1;
  }

  __shared__ short lA[64*128];
  __shared__ short lB[128*128];
  __shared__ float redbuf[64];

  const int t = threadIdx.x;
  {
    const char* src = (const char*)(utils + (size_t)u*BSE + (size_t)pt*64*EE);
#pragma unroll
    for (int c = 0; c < 8; ++c) {
      int off = c*4096 + t*16;
      float4 v = *(const float4*)(src + off);
      s16x4 h;
      h.x = (short)f2bf(v.x); h.y = (short)f2bf(v.y);
      h.z = (short)f2bf(v.z); h.w = (short)f2bf(v.w);
      *(s16x4*)((char*)lA + (off >> 1)) = h;
    }
    const char* wsrc = (const char*)W;
#pragma unroll
    for (int c = 0; c < 16; ++c) {
      int off = c*4096 + t*16;
      float4 v = *(const float4*)(wsrc + off);
      s16x4 h;
      h.x = (short)f2bf(v.x); h.y = (short)f2bf(v.y);
      h.z = (short)f2bf(v.z); h.w = (short)f2bf(v.w);
      *(s16x4*)((char*)lB + (off >> 1)) = h;
    }
  }
  __syncthreads();

  const int lane = t & 63, wv = t >> 6;
  const int wrE = wv & 1, wcE = wv >> 1;
  const int cL = lane & 15, r4 = (lane >> 4) * 4, k8 = (lane >> 4) * 8;

  f32x4 acc[2][4];
#pragma unroll
  for (int i = 0; i < 2; ++i)
#pragma unroll
    for (int j = 0; j < 4; ++j) acc[i][j] = f32x4{0.f, 0.f, 0.f, 0.f};

#pragma unroll
  for (int kk = 0; kk < 4; ++kk) {
    s16x8 av[2], bv[4];
#pragma unroll
    for (int i = 0; i < 2; ++i)
      av[i] = *(const s16x8*)&lA[(wrE*32 + i*16 + cL)*128 + kk*32 + k8];
#pragma unroll
    for (int j = 0; j < 4; ++j)
      bv[j] = *(const s16x8*)&lB[(wcE*64 + j*16 + cL)*128 + kk*32 + k8];
#pragma unroll
    for (int i = 0; i < 2; ++i)
#pragma unroll
      for (int j = 0; j < 4; ++j)
        acc[i][j] = mfma16(av[i], bv[j], acc[i][j]);
  }

  if (mode == 0) {
    const float* w2 = un_w2 + u*EE;
    float s[2][4];
#pragma unroll
    for (int i = 0; i < 2; ++i)
#pragma unroll
      for (int r = 0; r < 4; ++r) s[i][r] = 0.f;
#pragma unroll
    for (int i = 0; i < 2; ++i) {
#pragma unroll
      for (int j = 0; j < 4; ++j) {
        int o = wcE*64 + j*16 + cL;
        float bv2 = bias[o], w2v = w2[o];
#pragma unroll
        for (int r = 0; r < 4; ++r) {
          float v = acc[i][j][r] + bv2;
          v = v > 0.f ? v : 0.f;
          s[i][r] += v * w2v;
        }
      }
    }
#pragma unroll
    for (int msk = 1; msk < 16; msk <<= 1)
#pragma unroll
      for (int i = 0; i < 2; ++i)
#pragma unroll
        for (int r = 0; r < 4; ++r)
          s[i][r] += __shfl_xor(s[i][r], msk, 64);
    if (t < 64) redbuf[t] = 0.f;
    __syncthreads();
    if (cL == 0) {
#pragma unroll
      for (int i = 0; i < 2; ++i)
#pragma unroll
        for (int r = 0; r < 4; ++r)
          atomicAdd(&redbuf[wrE*32 + i*16 + r4 + r], s[i][r]);
    }
    __syncthreads();
    if (t < 64) unp[(size_t)u*NB*NS + (size_t)pt*64 + t] = redbuf[t] + un_b2[u];
  } else {
    float nrm[2][4];
#pragma unroll
    for (int i = 0; i < 2; ++i)
#pragma unroll
      for (int r = 0; r < 4; ++r) nrm[i][r] = 0.f;
#pragma unroll
    for (int i = 0; i < 2; ++i) {
#pragma unroll
      for (int j = 0; j < 4; ++j) {
        int o = wcE*64 + j*16 + cL;
        float bv2 = bias[o];
#pragma unroll
        for (int r = 0; r < 4; ++r) {
          acc[i][j][r] += bv2;
          nrm[i][r] += acc[i][j][r] * acc[i][j][r];
        }
      }
    }
#pragma unroll
    for (int msk = 1; msk < 16; msk <<= 1)
#pragma unroll
      for (int i = 0; i < 2; ++i)
#pragma unroll
        for (int r = 0; r < 4; ++r)
          nrm[i][r] += __shfl_xor(nrm[i][r], msk, 64);
    if (t < 64) redbuf[t] = 0.f;
    __syncthreads();
    if (cL == 0) {
#pragma unroll
      for (int i = 0; i < 2; ++i)
#pragma unroll
        for (int r = 0; r < 4; ++r)
          atomicAdd(&redbuf[wrE*32 + i*16 + r4 + r], nrm[i][r]);
    }
    __syncthreads();
#pragma unroll
    for (int i = 0; i < 2; ++i) {
#pragma unroll
      for (int r = 0; r < 4; ++r) {
        float n = redbuf[wrE*32 + i*16 + r4 + r];
        float sc = 1.f / fmaxf(sqrtf(n), 1e-12f);
        size_t pbase = ((size_t)pt*64 + wrE*32 + i*16 + r4 + r) * EE;
#pragma unroll
        for (int j = 0; j < 4; ++j) {
          int o = wcE*64 + j*16 + cL;
          dst[pbase + o] = f2bf(acc[i][j][r] * sc);
        }
      }
    }
  }
}

// ================= pass 1: batch stats of S =================
// Block = (p, xt, yt): 128x128 tile. Loop b: MFMA S-tile, accumulate sum / sum^2.
__global__ __launch_bounds__(256, 1) void pass1_kernel(
    const unsigned short* __restrict__ emb,
    float* __restrict__ sumS, float* __restrict__ sumS2)
{
  const int bid = blockIdx.x;
  const int p = bid >> 6, xt = (bid >> 3) & 7, yt = bid & 7;
  const char* Xe = (const char*)(emb + (size_t)(2*p)*BSE + (size_t)xt*128*EE);
  const char* Ye = (const char*)(emb + (size_t)(2*p+1)*BSE + (size_t)yt*128*EE);
  __shared__ short lA[128*128];
  __shared__ short lB[128*128];
  const int t = threadIdx.x, lane = t & 63, wv = t >> 6;
  const int wr = wv >> 1, wc = wv & 1, cL = lane & 15, r4 = (lane >> 4) * 4, k8 = (lane >> 4) * 8;

  f32x4 sS[4][4], sQ[4][4];
#pragma unroll
  for (int i = 0; i < 4; ++i)
#pragma unroll
    for (int j = 0; j < 4; ++j) { sS[i][j] = f32x4{0.f,0.f,0.f,0.f}; sQ[i][j] = f32x4{0.f,0.f,0.f,0.f}; }

  for (int b = 0; b < NB; ++b) {
    __syncthreads();
    const char* Ab = Xe + (size_t)b * NS * EE * 2;
    const char* Bb = Ye + (size_t)b * NS * EE * 2;
#pragma unroll
    for (int c = 0; c < 8; ++c) {
      int off = c*4096 + t*16;
      *(s16x8*)((char*)lA + off) = *(const s16x8*)(Ab + off);
      *(s16x8*)((char*)lB + off) = *(const s16x8*)(Bb + off);
    }
    __syncthreads();
    f32x4 acc[4][4];
#pragma unroll
    for (int i = 0; i < 4; ++i)
#pragma unroll
      for (int j = 0; j < 4; ++j) acc[i][j] = f32x4{0.f,0.f,0.f,0.f};
#pragma unroll
    for (int kk = 0; kk < 4; ++kk) {
      s16x8 av[4], bv[4];
#pragma unroll
      for (int i = 0; i < 4; ++i)
        av[i] = *(const s16x8*)&lA[(wr*64 + i*16 + cL)*128 + kk*32 + k8];
#pragma unroll
      for (int j = 0; j < 4; ++j)
        bv[j] = *(const s16x8*)&lB[(wc*64 + j*16 + cL)*128 + kk*32 + k8];
#pragma unroll
      for (int i = 0; i < 4; ++i)
#pragma unroll
        for (int j = 0; j < 4; ++j)
          acc[i][j] = mfma16(av[i], bv[j], acc[i][j]);
    }
#pragma unroll
    for (int i = 0; i < 4; ++i)
#pragma unroll
      for (int j = 0; j < 4; ++j) {
        sS[i][j] += acc[i][j];
        sQ[i][j] += acc[i][j] * acc[i][j];
      }
  }
  float* oS = sumS  + (size_t)p * NS * NS;
  float* oQ = sumS2 + (size_t)p * NS * NS;
#pragma unroll
  for (int i = 0; i < 4; ++i)
#pragma unroll
    for (int j = 0; j < 4; ++j)
#pragma unroll
      for (int r = 0; r < 4; ++r) {
        int row = xt*128 + wr*64 + i*16 + r4 + r;
        int col = yt*128 + wc*64 + j*16 + cL;
        oS[(size_t)row*NS + col] = sS[i][j][r];
        oQ[(size_t)row*NS + col] = sQ[i][j][r];
      }
}

// ================= stats: rstd -> R(bf16), constants cX / cY =================
__global__ void stats_kernel(
    const float* __restrict__ sumS, const float* __restrict__ sumS2,
    const float* __restrict__ sp_g, const float* __restrict__ sp_b,
    const float* __restrict__ sp_mxw, const float* __restrict__ sp_mxb,
    const float* __restrict__ pw_g, const float* __restrict__ pw_b,
    const float* __restrict__ pw_mxw, const float* __restrict__ pw_mxb,
    const float* __restrict__ pw_myw,
    unsigned short* __restrict__ Rb, float* __restrict__ cX, float* __restrict__ cY)
{
  const int p = blockIdx.x >> 10, x = blockIdx.x & 1023, t = threadIdx.x;
  const float* g; const float* bb; const float* mxw; float mxb; const float* myw = nullptr;
  if (p < 3) {
    g = sp_g + (size_t)p*NS*NS; bb = sp_b + (size_t)p*NS*NS;
    mxw = sp_mxw + p*NS; mxb = sp_mxb[p];
  } else {
    int q = p - 3;
    g = pw_g + (size_t)q*NS*NS; bb = pw_b + (size_t)q*NS*NS;
    mxw = pw_mxw + q*NS; mxb = pw_mxb[q]; myw = pw_myw + q*NS;
  }
  const size_t ro = (size_t)p*NS*NS + (size_t)x*NS;
  const size_t gro = (size_t)x*NS;
  const int y = t * 4;
  float4 s4 = *(const float4*)(sumS + ro + y);
  float4 q4 = *(const float4*)(sumS2 + ro + y);
  float4 g4 = *(const float4*)(g + gro + y);
  float4 b4 = *(const float4*)(bb + gro + y);
  float4 m4 = *(const float4*)(mxw + y);
  const float mywx = myw ? myw[x] : 0.f;
  float partial = 0.f;
  s16x4 rq;
  float ct[4];
  {
    const float inv = 1.f / 32.f;
    float sv[4] = {s4.x, s4.y, s4.z, s4.w};
    float qv[4] = {q4.x, q4.y, q4.z, q4.w};
    float gv[4] = {g4.x, g4.y, g4.z, g4.w};
    float bv[4] = {b4.x, b4.y, b4.z, b4.w};
    float mw[4] = {m4.x, m4.y, m4.z, m4.w};
#pragma unroll
    for (int c = 0; c < 4; ++c) {
      float mean = sv[c] * inv;
      float var  = qv[c] * inv - mean * mean;
      float rstd = rsqrtf(var + 1e-5f);
      unsigned short rh = f2bf(gv[c] * rstd);
      rq[c] = (short)rh;
      float Rq = bf2f(rh);
      float cterm = bv[c] - Rq * mean;
      partial += mw[c] * cterm;
      ct[c] = cterm;
    }
  }
  *(s16x4*)(Rb + ro + y) = rq;
  if (myw) {
#pragma unroll
    for (int c = 0; c < 4; ++c) atomicAdd(&cY[p*NS + y + c], mywx * ct[c]);
  }
  __shared__ float sred[256];
  sred[t] = partial;
  __syncthreads();
  if (t < 128) sred[t] += sred[t + 128];
  __syncthreads();
  if (t < 64) {
    float v = sred[t] + sred[t + 64];
#pragma unroll
    for (int msk = 1; msk < 64; msk <<= 1) v += __shfl_xor(v, msk, 64);
    if (t == 0) cX[p*NS + x] = v + mxb;
  }
}

// ================= pass 2: recompute S, weighted reductions =================
// Block = (p, b, xt). Loops yt. potX exclusive per block; potY via atomics.
__global__ __launch_bounds__(256, 2) void pass2_kernel(
    const unsigned short* __restrict__ emb, const unsigned short* __restrict__ Rb,
    const float* __restrict__ sp_mxw, const float* __restrict__ pw_mxw,
    const float* __restrict__ pw_myw,
    float* __restrict__ potX, float* __restrict__ potY)
{
  const int bid = blockIdx.x;
  const int p = bid >> 8, b = (bid >> 3) & 31, xt = bid & 7;
  const char* Ae = (const char*)(emb + (size_t)(2*p)*BSE + ((size_t)b*NS + (size_t)xt*128)*EE);
  const char* Be = (const char*)(emb + (size_t)(2*p+1)*BSE + (size_t)b*NS*EE);
  const unsigned short* Rp = Rb + (size_t)p*NS*NS;
  const float* mxw = (p < 3) ? (sp_mxw + p*NS) : (pw_mxw + (p-3)*NS);
  const float* myw = (p < 3) ? nullptr : (pw_myw + (p-3)*NS);
  __shared__ short lA[128*128];
  __shared__ short lB[128*128];
  __shared__ float pxbuf[128];
  const int t = threadIdx.x, lane = t & 63, wv = t >> 6;
  const int wr = wv >> 1, wc = wv & 1, cL = lane & 15, r4 = (lane >> 4) * 4, k8 = (lane >> 4) * 8;

#pragma unroll
  for (int c = 0; c < 8; ++c) {
    int off = c*4096 + t*16;
    *(s16x8*)((char*)lA + off) = *(const s16x8*)(Ae + off);
  }
  float px[4][4];
#pragma unroll
  for (int i = 0; i < 4; ++i)
#pragma unroll
    for (int r = 0; r < 4; ++r) px[i][r] = 0.f;
  float mywv[4][4];
  if (myw) {
#pragma unroll
    for (int i = 0; i < 4; ++i)
#pragma unroll
      for (int r = 0; r < 4; ++r)
        mywv[i][r] = myw[xt*128 + wr*64 + i*16 + r4 + r];
  }

  for (int yt = 0; yt < 8; ++yt) {
    __syncthreads();
#pragma unroll
    for (int c = 0; c < 8; ++c) {
      int off = c*4096 + t*16;
      *(s16x8*)((char*)lB + off) = *(const s16x8*)(Be + (size_t)yt*32768 + off);
    }
    __syncthreads();
    f32x4 acc[4][4];
#pragma unroll
    for (int i = 0; i < 4; ++i)
#pragma unroll
      for (int j = 0; j < 4; ++j) acc[i][j] = f32x4{0.f,0.f,0.f,0.f};
#pragma unroll
    for (int kk = 0; kk < 4; ++kk) {
      s16x8 av[4], bv[4];
#pragma unroll
      for (int i = 0; i < 4; ++i)
        av[i] = *(const s16x8*)&lA[(wr*64 + i*16 + cL)*128 + kk*32 + k8];
#pragma unroll
      for (int j = 0; j < 4; ++j)
        bv[j] = *(const s16x8*)&lB[(wc*64 + j*16 + cL)*128 + kk*32 + k8];
#pragma unroll
      for (int i = 0; i < 4; ++i)
#pragma unroll
        for (int j = 0; j < 4; ++j)
          acc[i][j] = mfma16(av[i], bv[j], acc[i][j]);
    }
    float mxl[4];
#pragma unroll
    for (int j = 0; j < 4; ++j) mxl[j] = mxw[yt*128 + wc*64 + j*16 + cL];

    if (myw) {
      float py[4] = {0.f, 0.f, 0.f, 0.f};
#pragma unroll
      for (int i = 0; i < 4; ++i) {
#pragma unroll
        for (int r = 0; r < 4; ++r) {
          const unsigned short* Rr = Rp + (size_t)(xt*128 + wr*64 + i*16 + r4 + r)*NS + yt*128;
          float pxa = 0.f;
#pragma unroll
          for (int j = 0; j < 4; ++j) {
            float Rv = bf2f(Rr[wc*64 + j*16 + cL]);
            float tt = Rv * acc[i][j][r];
            pxa += mxl[j] * tt;
            py[j] += mywv[i][r] * tt;
          }
          px[i][r] += pxa;
        }
      }
#pragma unroll
      for (int j = 0; j < 4; ++j) {
        py[j] += __shfl_xor(py[j], 16, 64);
        py[j] += __shfl_xor(py[j], 32, 64);
      }
      if ((lane >> 4) == 0) {
#pragma unroll
        for (int j = 0; j < 4; ++j)
          atomicAdd(&potY[((size_t)p*NB + b)*NS + yt*128 + wc*64 + j*16 + cL], py[j]);
      }
    } else {
#pragma unroll
      for (int i = 0; i < 4; ++i) {
#pragma unroll
        for (int r = 0; r < 4; ++r) {
          const unsigned short* Rr = Rp + (size_t)(xt*128 + wr*64 + i*16 + r4 + r)*NS + yt*128;
          float pxa = 0.f;
#pragma unroll
          for (int j = 0; j < 4; ++j) {
            float Rv = bf2f(Rr[wc*64 + j*16 + cL]);
            pxa += mxl[j] * (Rv * acc[i][j][r]);
          }
          px[i][r] += pxa;
        }
      }
    }
  }
#pragma unroll
  for (int msk = 1; msk < 16; msk <<= 1)
#pragma unroll
    for (int i = 0; i < 4; ++i)
#pragma unroll
      for (int r = 0; r < 4; ++r)
        px[i][r] += __shfl_xor(px[i][r], msk, 64);
  if (t < 128) pxbuf[t] = 0.f;
  __syncthreads();
  if (cL == 0) {
#pragma unroll
    for (int i = 0; i < 4; ++i)
#pragma unroll
      for (int r = 0; r < 4; ++r)
        atomicAdd(&pxbuf[wr*64 + i*16 + r4 + r], px[i][r]);
  }
  __syncthreads();
  if (t < 128) potX[((size_t)p*NB + b)*NS + (size_t)xt*128 + t] = pxbuf[t];
}

// ================= final: red -> softmax -> weighted sum of utils =================
__global__ __launch_bounds__(256, 4) void final_kernel(
    const float* __restrict__ utils, const float* __restrict__ unp,
    const float* __restrict__ potX, const float* __restrict__ potY,
    const float* __restrict__ cX, const float* __restrict__ cY,
    const float* __restrict__ pw_myb, const float* __restrict__ red_w,
    float* __restrict__ out)
{
  const int u = blockIdx.x >> 5, b = blockIdx.x & 31, t = threadIdx.x;
  const int lane = t & 63, wv = t >> 6;
  __shared__ float wts[1024];
  __shared__ float redA[4], redB[4];
  __shared__ float comb[128];
  const float* unpp  = unp  + ((size_t)u*NB + b)*NS;
  const float* selfX = potX + ((size_t)u*NB + b)*NS;
  const float* cXu   = cX + u*NS;
  const float rw0 = red_w[u*4+0], rw1 = red_w[u*4+1], rw2 = red_w[u*4+2], rw3 = red_w[u*4+3];
  const float *p2, *p3, *c2, *c3; float a2, a3;
  if (u == 0) {
    p2 = potX + ((size_t)3*NB + b)*NS; c2 = cX + 3*NS; a2 = 0.f;
    p3 = potX + ((size_t)4*NB + b)*NS; c3 = cX + 4*NS; a3 = 0.f;
  } else if (u == 1) {
    p2 = potY + ((size_t)3*NB + b)*NS; c2 = cY + 3*NS; a2 = pw_myb[0];
    p3 = potX + ((size_t)5*NB + b)*NS; c3 = cX + 5*NS; a3 = 0.f;
  } else {
    p2 = potY + ((size_t)4*NB + b)*NS; c2 = cY + 4*NS; a2 = pw_myb[1];
    p3 = potY + ((size_t)5*NB + b)*NS; c3 = cY + 5*NS; a3 = pw_myb[2];
  }
  float rv[4]; float lmax = -3.4e38f;
#pragma unroll
  for (int k = 0; k < 4; ++k) {
    int s = t*4 + k;
    float v = rw0*unpp[s] + rw1*(selfX[s] + cXu[s])
            + rw2*(p2[s] + c2[s] + a2) + rw3*(p3[s] + c3[s] + a3);
    rv[k] = v; lmax = fmaxf(lmax, v);
  }
#pragma unroll
  for (int msk = 1; msk < 64; msk <<= 1) lmax = fmaxf(lmax, __shfl_xor(lmax, msk, 64));
  if (lane == 0) redA[wv] = lmax;
  __syncthreads();
  const float gmax = fmaxf(fmaxf(redA[0], redA[1]), fmaxf(redA[2], redA[3]));
  float lsum = 0.f;
#pragma unroll
  for (int k = 0; k < 4; ++k) {
    float e2 = __expf(rv[k] - gmax);
    wts[t*4 + k] = e2; lsum += e2;
  }
#pragma unroll
  for (int msk = 1; msk < 64; msk <<= 1) lsum += __shfl_xor(lsum, msk, 64);
  if (lane == 0) redB[wv] = lsum;
  __syncthreads();
  const float inv = 1.f / (redB[0] + redB[1] + redB[2] + redB[3]);
  const int e = t & 127, half = t >> 7;
  const float* ub = utils + (size_t)u*BSE + (size_t)b*NS*EE;
  float acc = 0.f;
  const int s0 = half * 512;
#pragma unroll 8
  for (int s = s0; s < s0 + 512; ++s)
    acc += ub[(size_t)s*EE + e] * wts[s];
  if (half) comb[e] = acc;
  __syncthreads();
  if (!half) out[((size_t)u*NB + b)*EE + e] = (acc + comb[e]) * inv;
}

// ================= host launch =================
extern "C" void kernel_launch(void* const* d_in, const int* in_sizes, int n_in,
                              void* d_out, int out_size, void* d_ws, size_t ws_size,
                              hipStream_t stream)
{
  (void)in_sizes; (void)n_in; (void)out_size; (void)ws_size;
  const float* utils  = (const float*)d_in[0];
  const float* un_w1  = (const float*)d_in[1];
  const float* un_b1  = (const float*)d_in[2];
  const float* un_w2  = (const float*)d_in[3];
  const float* un_b2  = (const float*)d_in[4];
  const float* sp_wx  = (const float*)d_in[5];
  const float* sp_bx  = (const float*)d_in[6];
  const float* sp_wy  = (const float*)d_in[7];
  const float* sp_by  = (const float*)d_in[8];
  const float* sp_g   = (const float*)d_in[9];
  const float* sp_b   = (const float*)d_in[10];
  const float* sp_mxw = (const float*)d_in[11];
  const float* sp_mxb = (const float*)d_in[12];
  const float* pw_wx  = (const float*)d_in[13];
  const float* pw_bx  = (const float*)d_in[14];
  const float* pw_wy  = (const float*)d_in[15];
  const float* pw_by  = (const float*)d_in[16];
  const float* pw_g   = (const float*)d_in[17];
  const float* pw_b   = (const float*)d_in[18];
  const float* pw_mxw = (const float*)d_in[19];
  const float* pw_mxb = (const float*)d_in[20];
  const float* pw_myw = (const float*)d_in[21];
  const float* pw_myb = (const float*)d_in[22];
  const float* red_w  = (const float*)d_in[23];
  float* out = (float*)d_out;
  char* ws = (char*)d_ws;

  unsigned short* embp  = (unsigned short*)(ws + EMB_OFF);
  float* unpp           = (float*)(ws + UNP_OFF);
  float* sumSp          = (float*)(ws + SUMS_OFF);
  float* sumS2p         = (float*)(ws + SUMS2_OFF);
  unsigned short* Rbp   = (unsigned short*)(ws + RB_OFF);
  float* cXp            = (float*)(ws + CX_OFF);
  float* potXp          = (float*)(ws + POTX_OFF);
  float* potYp          = (float*)(ws + POTY_OFF);
  float* cYp            = (float*)(ws + CY_OFF);

  hipMemsetAsync(ws + POTY_OFF, 0, (6ull*NB*NS + 6ull*NS) * 4, stream);

  embed_kernel<<<dim3(7680), dim3(256), 0, stream>>>(
      utils, un_w1, un_b1, un_w2, un_b2, sp_wx, sp_bx, sp_wy, sp_by,
      pw_wx, pw_bx, pw_wy, pw_by, embp, unpp);
  pass1_kernel<<<dim3(384), dim3(256), 0, stream>>>(embp, sumSp, sumS2p);
  stats_kernel<<<dim3(6144), dim3(256), 0, stream>>>(
      sumSp, sumS2p, sp_g, sp_b, sp_mxw, sp_mxb,
      pw_g, pw_b, pw_mxw, pw_mxb, pw_myw, Rbp, cXp, cYp);
  pass2_kernel<<<dim3(1536), dim3(256), 0, stream>>>(
      embp, Rbp, sp_mxw, pw_mxw, pw_myw, potXp, potYp);
  final_kernel<<<dim3(96), dim3(256), 0, stream>>>(
      utils, unpp, potXp, potYp, cXp, cYp, pw_myb, red_w, out);
}

// Round 2
// 521.295 us; speedup vs baseline: 1.3028x; 1.3028x over previous
//
#include <hip/hip_runtime.h>
#include <math.h>

constexpr int EE = 128;    // embedding dim
constexpr int NS = 1024;   // spatial S
constexpr int NB = 32;     // batch
constexpr size_t BSE = (size_t)NB * NS * EE;  // 4194304 elems per (b,s,e) array

typedef __attribute__((ext_vector_type(4))) float f32x4;
typedef __attribute__((ext_vector_type(8))) short s16x8;
typedef __attribute__((ext_vector_type(4))) short s16x4;
typedef __attribute__((ext_vector_type(8))) __bf16 bf16v8;

__device__ __forceinline__ f32x4 mfma16(s16x8 a, s16x8 b, f32x4 c) {
  return __builtin_amdgcn_mfma_f32_16x16x32_bf16(
      __builtin_bit_cast(bf16v8, a), __builtin_bit_cast(bf16v8, b), c, 0, 0, 0);
}

__device__ __forceinline__ unsigned short f2bf(float f) {
  unsigned u = __builtin_bit_cast(unsigned, f);
  u += 0x7FFFu + ((u >> 16) & 1u);
  return (unsigned short)(u >> 16);
}
__device__ __forceinline__ float bf2f(unsigned short h) {
  unsigned u = ((unsigned)h) << 16;
  return __builtin_bit_cast(float, u);
}

// LDS XOR swizzle: rows are 256B; XOR the 16B-slot index (bits 4-6) with row&7.
// Applied identically on staged writes and fragment reads (both-sides rule).
__device__ __forceinline__ int swz(int byte) {
  return byte ^ (((byte >> 8) & 7) << 4);
}

// ---------------- workspace layout (bytes) ----------------
constexpr size_t EMB_OFF   = 0;                                   // 12 bf16 arrays [p][side][b*S+s][e]
constexpr size_t UNP_OFF   = EMB_OFF + 12ull * BSE * 2;           // f32 [3][B][S]
constexpr size_t SUMS_OFF  = UNP_OFF + 3ull * NB * NS * 4;        // f32 [6][S][S]
constexpr size_t SUMS2_OFF = SUMS_OFF + 6ull * NS * NS * 4;       // f32 [6][S][S]
constexpr size_t RB_OFF    = SUMS2_OFF + 6ull * NS * NS * 4;      // bf16 [6][S][S]
constexpr size_t CX_OFF    = RB_OFF + 6ull * NS * NS * 2;         // f32 [6][S]
constexpr size_t POTX_OFF  = CX_OFF + 6ull * NS * 4;              // f32 [6][B][S]
constexpr size_t POTY_OFF  = POTX_OFF + 6ull * NB * NS * 4;       // f32 [6][B][S]  (zeroed)
constexpr size_t CY_OFF    = POTY_OFF + 6ull * NB * NS * 4;       // f32 [6][S]     (zeroed)

// ================= embed kernel =================
// job = u*5 + m;  m: 0=unary, 1=sp_x, 2=sp_y, 3/4 = pair-side embeds of util u.
// Block: 64 positions x 128 outputs, K=128, 4 waves (2 pos-halves x 2 out-halves).
__global__ __launch_bounds__(256, 2) void embed_kernel(
    const float* __restrict__ utils,
    const float* __restrict__ un_w1, const float* __restrict__ un_b1,
    const float* __restrict__ un_w2, const float* __restrict__ un_b2,
    const float* __restrict__ sp_wx, const float* __restrict__ sp_bx,
    const float* __restrict__ sp_wy, const float* __restrict__ sp_by,
    const float* __restrict__ pw_wx, const float* __restrict__ pw_bx,
    const float* __restrict__ pw_wy, const float* __restrict__ pw_by,
    unsigned short* __restrict__ emb, float* __restrict__ unp)
{
  const int job = blockIdx.x >> 9;
  const int pt  = blockIdx.x & 511;
  const int u = job / 5, m = job % 5;

  const float* W; const float* bias;
  unsigned short* dst = nullptr;
  int mode;
  if (m == 0)      { W = un_w1 + u*EE*EE; bias = un_b1 + u*EE; mode = 0; }
  else if (m == 1) { W = sp_wx + u*EE*EE; bias = sp_bx + u*EE; dst = emb + (size_t)(2*u)*BSE;   mode = 1; }
  else if (m == 2) { W = sp_wy + u*EE*EE; bias = sp_by + u*EE; dst = emb + (size_t)(2*u+1)*BSE; mode = 1; }
  else {
    int q, side;
    if (u == 0)      { q = (m == 3) ? 0 : 1; side = 0; }
    else if (u == 1) { if (m == 3) { q = 0; side = 1; } else { q = 2; side = 0; } }
    else             { q = (m == 3) ? 1 : 2; side = 1; }
    W    = (side == 0 ? pw_wx : pw_wy) + q*EE*EE;
    bias = (side == 0 ? pw_bx : pw_by) + q*EE;
    dst  = emb + (size_t)(2*(3+q)+side)*BSE;
    mode = 1;
  }

  __shared__ short lA[64*128];
  __shared__ short lB[128*128];
  __shared__ float redbuf[64];

  const int t = threadIdx.x;
  {
    const char* src = (const char*)(utils + (size_t)u*BSE + (size_t)pt*64*EE);
#pragma unroll
    for (int c = 0; c < 8; ++c) {
      int off = c*4096 + t*16;
      float4 v = *(const float4*)(src + off);
      s16x4 h;
      h.x = (short)f2bf(v.x); h.y = (short)f2bf(v.y);
      h.z = (short)f2bf(v.z); h.w = (short)f2bf(v.w);
      *(s16x4*)((char*)lA + swz(off >> 1)) = h;
    }
    const char* wsrc = (const char*)W;
#pragma unroll
    for (int c = 0; c < 16; ++c) {
      int off = c*4096 + t*16;
      float4 v = *(const float4*)(wsrc + off);
      s16x4 h;
      h.x = (short)f2bf(v.x); h.y = (short)f2bf(v.y);
      h.z = (short)f2bf(v.z); h.w = (short)f2bf(v.w);
      *(s16x4*)((char*)lB + swz(off >> 1)) = h;
    }
  }
  __syncthreads();

  const int lane = t & 63, wv = t >> 6;
  const int wrE = wv & 1, wcE = wv >> 1;
  const int cL = lane & 15, r4 = (lane >> 4) * 4, k8 = (lane >> 4) * 8;

  f32x4 acc[2][4];
#pragma unroll
  for (int i = 0; i < 2; ++i)
#pragma unroll
    for (int j = 0; j < 4; ++j) acc[i][j] = f32x4{0.f, 0.f, 0.f, 0.f};

#pragma unroll
  for (int kk = 0; kk < 4; ++kk) {
    s16x8 av[2], bv[4];
#pragma unroll
    for (int i = 0; i < 2; ++i) {
      int row = wrE*32 + i*16 + cL;
      av[i] = *(const s16x8*)((const char*)lA + swz(row*256 + kk*64 + k8*2));
    }
#pragma unroll
    for (int j = 0; j < 4; ++j) {
      int row = wcE*64 + j*16 + cL;
      bv[j] = *(const s16x8*)((const char*)lB + swz(row*256 + kk*64 + k8*2));
    }
#pragma unroll
    for (int i = 0; i < 2; ++i)
#pragma unroll
      for (int j = 0; j < 4; ++j)
        acc[i][j] = mfma16(av[i], bv[j], acc[i][j]);
  }

  if (mode == 0) {
    const float* w2 = un_w2 + u*EE;
    float s[2][4];
#pragma unroll
    for (int i = 0; i < 2; ++i)
#pragma unroll
      for (int r = 0; r < 4; ++r) s[i][r] = 0.f;
#pragma unroll
    for (int i = 0; i < 2; ++i) {
#pragma unroll
      for (int j = 0; j < 4; ++j) {
        int o = wcE*64 + j*16 + cL;
        float bv2 = bias[o], w2v = w2[o];
#pragma unroll
        for (int r = 0; r < 4; ++r) {
          float v = acc[i][j][r] + bv2;
          v = v > 0.f ? v : 0.f;
          s[i][r] += v * w2v;
        }
      }
    }
#pragma unroll
    for (int msk = 1; msk < 16; msk <<= 1)
#pragma unroll
      for (int i = 0; i < 2; ++i)
#pragma unroll
        for (int r = 0; r < 4; ++r)
          s[i][r] += __shfl_xor(s[i][r], msk, 64);
    if (t < 64) redbuf[t] = 0.f;
    __syncthreads();
    if (cL == 0) {
#pragma unroll
      for (int i = 0; i < 2; ++i)
#pragma unroll
        for (int r = 0; r < 4; ++r)
          atomicAdd(&redbuf[wrE*32 + i*16 + r4 + r], s[i][r]);
    }
    __syncthreads();
    if (t < 64) unp[(size_t)u*NB*NS + (size_t)pt*64 + t] = redbuf[t] + un_b2[u];
  } else {
    float nrm[2][4];
#pragma unroll
    for (int i = 0; i < 2; ++i)
#pragma unroll
      for (int r = 0; r < 4; ++r) nrm[i][r] = 0.f;
#pragma unroll
    for (int i = 0; i < 2; ++i) {
#pragma unroll
      for (int j = 0; j < 4; ++j) {
        int o = wcE*64 + j*16 + cL;
        float bv2 = bias[o];
#pragma unroll
        for (int r = 0; r < 4; ++r) {
          acc[i][j][r] += bv2;
          nrm[i][r] += acc[i][j][r] * acc[i][j][r];
        }
      }
    }
#pragma unroll
    for (int msk = 1; msk < 16; msk <<= 1)
#pragma unroll
      for (int i = 0; i < 2; ++i)
#pragma unroll
        for (int r = 0; r < 4; ++r)
          nrm[i][r] += __shfl_xor(nrm[i][r], msk, 64);
    if (t < 64) redbuf[t] = 0.f;
    __syncthreads();
    if (cL == 0) {
#pragma unroll
      for (int i = 0; i < 2; ++i)
#pragma unroll
        for (int r = 0; r < 4; ++r)
          atomicAdd(&redbuf[wrE*32 + i*16 + r4 + r], nrm[i][r]);
    }
    __syncthreads();
#pragma unroll
    for (int i = 0; i < 2; ++i) {
#pragma unroll
      for (int r = 0; r < 4; ++r) {
        float n = redbuf[wrE*32 + i*16 + r4 + r];
        float sc = 1.f / fmaxf(sqrtf(n), 1e-12f);
        size_t pbase = ((size_t)pt*64 + wrE*32 + i*16 + r4 + r) * EE;
#pragma unroll
        for (int j = 0; j < 4; ++j) {
          int o = wcE*64 + j*16 + cL;
          dst[pbase + o] = f2bf(acc[i][j][r] * sc);
        }
      }
    }
  }
}

// ================= pass 1: batch stats of S =================
// Block = (p, xt, yt): 128x128 tile. Loop b: MFMA S-tile, accumulate sum / sum^2.
__global__ __launch_bounds__(256, 1) void pass1_kernel(
    const unsigned short* __restrict__ emb,
    float* __restrict__ sumS, float* __restrict__ sumS2)
{
  const int bid = blockIdx.x;
  const int p = bid >> 6, xt = (bid >> 3) & 7, yt = bid & 7;
  const char* Xe = (const char*)(emb + (size_t)(2*p)*BSE + (size_t)xt*128*EE);
  const char* Ye = (const char*)(emb + (size_t)(2*p+1)*BSE + (size_t)yt*128*EE);
  __shared__ short lA[128*128];
  __shared__ short lB[128*128];
  const int t = threadIdx.x, lane = t & 63, wv = t >> 6;
  const int wr = wv >> 1, wc = wv & 1, cL = lane & 15, r4 = (lane >> 4) * 4, k8 = (lane >> 4) * 8;

  f32x4 sS[4][4], sQ[4][4];
#pragma unroll
  for (int i = 0; i < 4; ++i)
#pragma unroll
    for (int j = 0; j < 4; ++j) { sS[i][j] = f32x4{0.f,0.f,0.f,0.f}; sQ[i][j] = f32x4{0.f,0.f,0.f,0.f}; }

  for (int b = 0; b < NB; ++b) {
    __syncthreads();
    const char* Ab = Xe + (size_t)b * NS * EE * 2;
    const char* Bb = Ye + (size_t)b * NS * EE * 2;
#pragma unroll
    for (int c = 0; c < 8; ++c) {
      int off = c*4096 + t*16;
      int so = swz(off);
      *(s16x8*)((char*)lA + so) = *(const s16x8*)(Ab + off);
      *(s16x8*)((char*)lB + so) = *(const s16x8*)(Bb + off);
    }
    __syncthreads();
    f32x4 acc[4][4];
#pragma unroll
    for (int i = 0; i < 4; ++i)
#pragma unroll
      for (int j = 0; j < 4; ++j) acc[i][j] = f32x4{0.f,0.f,0.f,0.f};
#pragma unroll
    for (int kk = 0; kk < 4; ++kk) {
      s16x8 av[4], bv[4];
#pragma unroll
      for (int i = 0; i < 4; ++i) {
        int row = wr*64 + i*16 + cL;
        av[i] = *(const s16x8*)((const char*)lA + swz(row*256 + kk*64 + k8*2));
      }
#pragma unroll
      for (int j = 0; j < 4; ++j) {
        int row = wc*64 + j*16 + cL;
        bv[j] = *(const s16x8*)((const char*)lB + swz(row*256 + kk*64 + k8*2));
      }
#pragma unroll
      for (int i = 0; i < 4; ++i)
#pragma unroll
        for (int j = 0; j < 4; ++j)
          acc[i][j] = mfma16(av[i], bv[j], acc[i][j]);
    }
#pragma unroll
    for (int i = 0; i < 4; ++i)
#pragma unroll
      for (int j = 0; j < 4; ++j) {
        sS[i][j] += acc[i][j];
        sQ[i][j] += acc[i][j] * acc[i][j];
      }
  }
  float* oS = sumS  + (size_t)p * NS * NS;
  float* oQ = sumS2 + (size_t)p * NS * NS;
#pragma unroll
  for (int i = 0; i < 4; ++i)
#pragma unroll
    for (int j = 0; j < 4; ++j)
#pragma unroll
      for (int r = 0; r < 4; ++r) {
        int row = xt*128 + wr*64 + i*16 + r4 + r;
        int col = yt*128 + wc*64 + j*16 + cL;
        oS[(size_t)row*NS + col] = sS[i][j][r];
        oQ[(size_t)row*NS + col] = sQ[i][j][r];
      }
}

// ================= stats: rstd -> R(bf16), constants cX / cY =================
__global__ void stats_kernel(
    const float* __restrict__ sumS, const float* __restrict__ sumS2,
    const float* __restrict__ sp_g, const float* __restrict__ sp_b,
    const float* __restrict__ sp_mxw, const float* __restrict__ sp_mxb,
    const float* __restrict__ pw_g, const float* __restrict__ pw_b,
    const float* __restrict__ pw_mxw, const float* __restrict__ pw_mxb,
    const float* __restrict__ pw_myw,
    unsigned short* __restrict__ Rb, float* __restrict__ cX, float* __restrict__ cY)
{
  const int p = blockIdx.x >> 10, x = blockIdx.x & 1023, t = threadIdx.x;
  const float* g; const float* bb; const float* mxw; float mxb; const float* myw = nullptr;
  if (p < 3) {
    g = sp_g + (size_t)p*NS*NS; bb = sp_b + (size_t)p*NS*NS;
    mxw = sp_mxw + p*NS; mxb = sp_mxb[p];
  } else {
    int q = p - 3;
    g = pw_g + (size_t)q*NS*NS; bb = pw_b + (size_t)q*NS*NS;
    mxw = pw_mxw + q*NS; mxb = pw_mxb[q]; myw = pw_myw + q*NS;
  }
  const size_t ro = (size_t)p*NS*NS + (size_t)x*NS;
  const size_t gro = (size_t)x*NS;
  const int y = t * 4;
  float4 s4 = *(const float4*)(sumS + ro + y);
  float4 q4 = *(const float4*)(sumS2 + ro + y);
  float4 g4 = *(const float4*)(g + gro + y);
  float4 b4 = *(const float4*)(bb + gro + y);
  float4 m4 = *(const float4*)(mxw + y);
  const float mywx = myw ? myw[x] : 0.f;
  float partial = 0.f;
  s16x4 rq;
  float ct[4];
  {
    const float inv = 1.f / 32.f;
    float sv[4] = {s4.x, s4.y, s4.z, s4.w};
    float qv[4] = {q4.x, q4.y, q4.z, q4.w};
    float gv[4] = {g4.x, g4.y, g4.z, g4.w};
    float bv[4] = {b4.x, b4.y, b4.z, b4.w};
    float mw[4] = {m4.x, m4.y, m4.z, m4.w};
#pragma unroll
    for (int c = 0; c < 4; ++c) {
      float mean = sv[c] * inv;
      float var  = qv[c] * inv - mean * mean;
      float rstd = rsqrtf(var + 1e-5f);
      unsigned short rh = f2bf(gv[c] * rstd);
      rq[c] = (short)rh;
      float Rq = bf2f(rh);
      float cterm = bv[c] - Rq * mean;
      partial += mw[c] * cterm;
      ct[c] = cterm;
    }
  }
  *(s16x4*)(Rb + ro + y) = rq;
  if (myw) {
#pragma unroll
    for (int c = 0; c < 4; ++c) atomicAdd(&cY[p*NS + y + c], mywx * ct[c]);
  }
  __shared__ float sred[256];
  sred[t] = partial;
  __syncthreads();
  if (t < 128) sred[t] += sred[t + 128];
  __syncthreads();
  if (t < 64) {
    float v = sred[t] + sred[t + 64];
#pragma unroll
    for (int msk = 1; msk < 64; msk <<= 1) v += __shfl_xor(v, msk, 64);
    if (t == 0) cX[p*NS + x] = v + mxb;
  }
}

// ================= pass 2: recompute S, weighted reductions =================
// Block = (p, b, xt). Loops yt. potX exclusive per block; potY via atomics.
__global__ __launch_bounds__(256, 2) void pass2_kernel(
    const unsigned short* __restrict__ emb, const unsigned short* __restrict__ Rb,
    const float* __restrict__ sp_mxw, const float* __restrict__ pw_mxw,
    const float* __restrict__ pw_myw,
    float* __restrict__ potX, float* __restrict__ potY)
{
  const int bid = blockIdx.x;
  const int p = bid >> 8, b = (bid >> 3) & 31, xt = bid & 7;
  const char* Ae = (const char*)(emb + (size_t)(2*p)*BSE + ((size_t)b*NS + (size_t)xt*128)*EE);
  const char* Be = (const char*)(emb + (size_t)(2*p+1)*BSE + (size_t)b*NS*EE);
  const unsigned short* Rp = Rb + (size_t)p*NS*NS;
  const float* mxw = (p < 3) ? (sp_mxw + p*NS) : (pw_mxw + (p-3)*NS);
  const float* myw = (p < 3) ? nullptr : (pw_myw + (p-3)*NS);
  __shared__ short lA[128*128];
  __shared__ short lB[128*128];
  __shared__ float pxbuf[128];
  const int t = threadIdx.x, lane = t & 63, wv = t >> 6;
  const int wr = wv >> 1, wc = wv & 1, cL = lane & 15, r4 = (lane >> 4) * 4, k8 = (lane >> 4) * 8;

#pragma unroll
  for (int c = 0; c < 8; ++c) {
    int off = c*4096 + t*16;
    *(s16x8*)((char*)lA + swz(off)) = *(const s16x8*)(Ae + off);
  }
  float px[4][4];
#pragma unroll
  for (int i = 0; i < 4; ++i)
#pragma unroll
    for (int r = 0; r < 4; ++r) px[i][r] = 0.f;
  float mywv[4][4];
  if (myw) {
#pragma unroll
    for (int i = 0; i < 4; ++i)
#pragma unroll
      for (int r = 0; r < 4; ++r)
        mywv[i][r] = myw[xt*128 + wr*64 + i*16 + r4 + r];
  }

  for (int yt = 0; yt < 8; ++yt) {
    __syncthreads();
#pragma unroll
    for (int c = 0; c < 8; ++c) {
      int off = c*4096 + t*16;
      *(s16x8*)((char*)lB + swz(off)) = *(const s16x8*)(Be + (size_t)yt*32768 + off);
    }
    __syncthreads();
    f32x4 acc[4][4];
#pragma unroll
    for (int i = 0; i < 4; ++i)
#pragma unroll
      for (int j = 0; j < 4; ++j) acc[i][j] = f32x4{0.f,0.f,0.f,0.f};
#pragma unroll
    for (int kk = 0; kk < 4; ++kk) {
      s16x8 av[4], bv[4];
#pragma unroll
      for (int i = 0; i < 4; ++i) {
        int row = wr*64 + i*16 + cL;
        av[i] = *(const s16x8*)((const char*)lA + swz(row*256 + kk*64 + k8*2));
      }
#pragma unroll
      for (int j = 0; j < 4; ++j) {
        int row = wc*64 + j*16 + cL;
        bv[j] = *(const s16x8*)((const char*)lB + swz(row*256 + kk*64 + k8*2));
      }
#pragma unroll
      for (int i = 0; i < 4; ++i)
#pragma unroll
        for (int j = 0; j < 4; ++j)
          acc[i][j] = mfma16(av[i], bv[j], acc[i][j]);
    }
    float mxl[4];
#pragma unroll
    for (int j = 0; j < 4; ++j) mxl[j] = mxw[yt*128 + wc*64 + j*16 + cL];

    if (myw) {
      float py[4] = {0.f, 0.f, 0.f, 0.f};
#pragma unroll
      for (int i = 0; i < 4; ++i) {
#pragma unroll
        for (int r = 0; r < 4; ++r) {
          const unsigned short* Rr = Rp + (size_t)(xt*128 + wr*64 + i*16 + r4 + r)*NS + yt*128;
          float pxa = 0.f;
#pragma unroll
          for (int j = 0; j < 4; ++j) {
            float Rv = bf2f(Rr[wc*64 + j*16 + cL]);
            float tt = Rv * acc[i][j][r];
            pxa += mxl[j] * tt;
            py[j] += mywv[i][r] * tt;
          }
          px[i][r] += pxa;
        }
      }
#pragma unroll
      for (int j = 0; j < 4; ++j) {
        py[j] += __shfl_xor(py[j], 16, 64);
        py[j] += __shfl_xor(py[j], 32, 64);
      }
      if ((lane >> 4) == 0) {
#pragma unroll
        for (int j = 0; j < 4; ++j)
          atomicAdd(&potY[((size_t)p*NB + b)*NS + yt*128 + wc*64 + j*16 + cL], py[j]);
      }
    } else {
#pragma unroll
      for (int i = 0; i < 4; ++i) {
#pragma unroll
        for (int r = 0; r < 4; ++r) {
          const unsigned short* Rr = Rp + (size_t)(xt*128 + wr*64 + i*16 + r4 + r)*NS + yt*128;
          float pxa = 0.f;
#pragma unroll
          for (int j = 0; j < 4; ++j) {
            float Rv = bf2f(Rr[wc*64 + j*16 + cL]);
            pxa += mxl[j] * (Rv * acc[i][j][r]);
          }
          px[i][r] += pxa;
        }
      }
    }
  }
#pragma unroll
  for (int msk = 1; msk < 16; msk <<= 1)
#pragma unroll
    for (int i = 0; i < 4; ++i)
#pragma unroll
      for (int r = 0; r < 4; ++r)
        px[i][r] += __shfl_xor(px[i][r], msk, 64);
  if (t < 128) pxbuf[t] = 0.f;
  __syncthreads();
  if (cL == 0) {
#pragma unroll
    for (int i = 0; i < 4; ++i)
#pragma unroll
      for (int r = 0; r < 4; ++r)
        atomicAdd(&pxbuf[wr*64 + i*16 + r4 + r], px[i][r]);
  }
  __syncthreads();
  if (t < 128) potX[((size_t)p*NB + b)*NS + (size_t)xt*128 + t] = pxbuf[t];
}

// ================= final: red -> softmax -> weighted sum of utils =================
__global__ __launch_bounds__(256, 4) void final_kernel(
    const float* __restrict__ utils, const float* __restrict__ unp,
    const float* __restrict__ potX, const float* __restrict__ potY,
    const float* __restrict__ cX, const float* __restrict__ cY,
    const float* __restrict__ pw_myb, const float* __restrict__ red_w,
    float* __restrict__ out)
{
  const int u = blockIdx.x >> 5, b = blockIdx.x & 31, t = threadIdx.x;
  const int lane = t & 63, wv = t >> 6;
  __shared__ float wts[1024];
  __shared__ float redA[4], redB[4];
  __shared__ float comb[128];
  const float* unpp  = unp  + ((size_t)u*NB + b)*NS;
  const float* selfX = potX + ((size_t)u*NB + b)*NS;
  const float* cXu   = cX + u*NS;
  const float rw0 = red_w[u*4+0], rw1 = red_w[u*4+1], rw2 = red_w[u*4+2], rw3 = red_w[u*4+3];
  const float *p2, *p3, *c2, *c3; float a2, a3;
  if (u == 0) {
    p2 = potX + ((size_t)3*NB + b)*NS; c2 = cX + 3*NS; a2 = 0.f;
    p3 = potX + ((size_t)4*NB + b)*NS; c3 = cX + 4*NS; a3 = 0.f;
  } else if (u == 1) {
    p2 = potY + ((size_t)3*NB + b)*NS; c2 = cY + 3*NS; a2 = pw_myb[0];
    p3 = potX + ((size_t)5*NB + b)*NS; c3 = cX + 5*NS; a3 = 0.f;
  } else {
    p2 = potY + ((size_t)4*NB + b)*NS; c2 = cY + 4*NS; a2 = pw_myb[1];
    p3 = potY + ((size_t)5*NB + b)*NS; c3 = cY + 5*NS; a3 = pw_myb[2];
  }
  float rv[4]; float lmax = -3.4e38f;
#pragma unroll
  for (int k = 0; k < 4; ++k) {
    int s = t*4 + k;
    float v = rw0*unpp[s] + rw1*(selfX[s] + cXu[s])
            + rw2*(p2[s] + c2[s] + a2) + rw3*(p3[s] + c3[s] + a3);
    rv[k] = v; lmax = fmaxf(lmax, v);
  }
#pragma unroll
  for (int msk = 1; msk < 64; msk <<= 1) lmax = fmaxf(lmax, __shfl_xor(lmax, msk, 64));
  if (lane == 0) redA[wv] = lmax;
  __syncthreads();
  const float gmax = fmaxf(fmaxf(redA[0], redA[1]), fmaxf(redA[2], redA[3]));
  float lsum = 0.f;
#pragma unroll
  for (int k = 0; k < 4; ++k) {
    float e2 = __expf(rv[k] - gmax);
    wts[t*4 + k] = e2; lsum += e2;
  }
#pragma unroll
  for (int msk = 1; msk < 64; msk <<= 1) lsum += __shfl_xor(lsum, msk, 64);
  if (lane == 0) redB[wv] = lsum;
  __syncthreads();
  const float inv = 1.f / (redB[0] + redB[1] + redB[2] + redB[3]);
  const int e = t & 127, half = t >> 7;
  const float* ub = utils + (size_t)u*BSE + (size_t)b*NS*EE;
  float acc = 0.f;
  const int s0 = half * 512;
#pragma unroll 8
  for (int s = s0; s < s0 + 512; ++s)
    acc += ub[(size_t)s*EE + e] * wts[s];
  if (half) comb[e] = acc;
  __syncthreads();
  if (!half) out[((size_t)u*NB + b)*EE + e] = (acc + comb[e]) * inv;
}

// ================= host launch =================
extern "C" void kernel_launch(void* const* d_in, const int* in_sizes, int n_in,
                              void* d_out, int out_size, void* d_ws, size_t ws_size,
                              hipStream_t stream)
{
  (void)in_sizes; (void)n_in; (void)out_size; (void)ws_size;
  const float* utils  = (const float*)d_in[0];
  const float* un_w1  = (const float*)d_in[1];
  const float* un_b1  = (const float*)d_in[2];
  const float* un_w2  = (const float*)d_in[3];
  const float* un_b2  = (const float*)d_in[4];
  const float* sp_wx  = (const float*)d_in[5];
  const float* sp_bx  = (const float*)d_in[6];
  const float* sp_wy  = (const float*)d_in[7];
  const float* sp_by  = (const float*)d_in[8];
  const float* sp_g   = (const float*)d_in[9];
  const float* sp_b   = (const float*)d_in[10];
  const float* sp_mxw = (const float*)d_in[11];
  const float* sp_mxb = (const float*)d_in[12];
  const float* pw_wx  = (const float*)d_in[13];
  const float* pw_bx  = (const float*)d_in[14];
  const float* pw_wy  = (const float*)d_in[15];
  const float* pw_by  = (const float*)d_in[16];
  const float* pw_g   = (const float*)d_in[17];
  const float* pw_b   = (const float*)d_in[18];
  const float* pw_mxw = (const float*)d_in[19];
  const float* pw_mxb = (const float*)d_in[20];
  const float* pw_myw = (const float*)d_in[21];
  const float* pw_myb = (const float*)d_in[22];
  const float* red_w  = (const float*)d_in[23];
  float* out = (float*)d_out;
  char* ws = (char*)d_ws;

  unsigned short* embp  = (unsigned short*)(ws + EMB_OFF);
  float* unpp           = (float*)(ws + UNP_OFF);
  float* sumSp          = (float*)(ws + SUMS_OFF);
  float* sumS2p         = (float*)(ws + SUMS2_OFF);
  unsigned short* Rbp   = (unsigned short*)(ws + RB_OFF);
  float* cXp            = (float*)(ws + CX_OFF);
  float* potXp          = (float*)(ws + POTX_OFF);
  float* potYp          = (float*)(ws + POTY_OFF);
  float* cYp            = (float*)(ws + CY_OFF);

  hipMemsetAsync(ws + POTY_OFF, 0, (6ull*NB*NS + 6ull*NS) * 4, stream);

  embed_kernel<<<dim3(7680), dim3(256), 0, stream>>>(
      utils, un_w1, un_b1, un_w2, un_b2, sp_wx, sp_bx, sp_wy, sp_by,
      pw_wx, pw_bx, pw_wy, pw_by, embp, unpp);
  pass1_kernel<<<dim3(384), dim3(256), 0, stream>>>(embp, sumSp, sumS2p);
  stats_kernel<<<dim3(6144), dim3(256), 0, stream>>>(
      sumSp, sumS2p, sp_g, sp_b, sp_mxw, sp_mxb,
      pw_g, pw_b, pw_mxw, pw_mxb, pw_myw, Rbp, cXp, cYp);
  pass2_kernel<<<dim3(1536), dim3(256), 0, stream>>>(
      embp, Rbp, sp_mxw, pw_mxw, pw_myw, potXp, potYp);
  final_kernel<<<dim3(96), dim3(256), 0, stream>>>(
      utils, unpp, potXp, potYp, cXp, cYp, pw_myb, red_w, out);
}

// Round 3
// 370.304 us; speedup vs baseline: 1.8340x; 1.4078x over previous
//
#include <hip/hip_runtime.h>
#include <math.h>

constexpr int EE = 128;    // embedding dim
constexpr int NS = 1024;   // spatial S
constexpr int NB = 32;     // batch
constexpr size_t BSE = (size_t)NB * NS * EE;  // 4194304 elems per (b,s,e) array

typedef __attribute__((ext_vector_type(4))) float f32x4;
typedef __attribute__((ext_vector_type(8))) short s16x8;
typedef __attribute__((ext_vector_type(4))) short s16x4;
typedef __attribute__((ext_vector_type(8))) __bf16 bf16v8;

__device__ __forceinline__ f32x4 mfma16(s16x8 a, s16x8 b, f32x4 c) {
  return __builtin_amdgcn_mfma_f32_16x16x32_bf16(
      __builtin_bit_cast(bf16v8, a), __builtin_bit_cast(bf16v8, b), c, 0, 0, 0);
}

__device__ __forceinline__ unsigned short f2bf(float f) {
  unsigned u = __builtin_bit_cast(unsigned, f);
  u += 0x7FFFu + ((u >> 16) & 1u);
  return (unsigned short)(u >> 16);
}
__device__ __forceinline__ float bf2f(unsigned short h) {
  unsigned u = ((unsigned)h) << 16;
  return __builtin_bit_cast(float, u);
}

// LDS XOR swizzle: rows are 256B; XOR the 16B-slot index (bits 4-6) with row&7.
// Applied identically on staged writes and fragment reads (both-sides rule).
__device__ __forceinline__ int swz(int byte) {
  return byte ^ (((byte >> 8) & 7) << 4);
}

// ---------------- workspace layout (bytes) ----------------
constexpr size_t EMB_OFF   = 0;                                   // 12 bf16 arrays [p][side][b*S+s][e]
constexpr size_t UNP_OFF   = EMB_OFF + 12ull * BSE * 2;           // f32 [3][B][S]
constexpr size_t SUMS_OFF  = UNP_OFF + 3ull * NB * NS * 4;        // f32 [6][S][S]
constexpr size_t SUMS2_OFF = SUMS_OFF + 6ull * NS * NS * 4;       // f32 [6][S][S]
constexpr size_t RB_OFF    = SUMS2_OFF + 6ull * NS * NS * 4;      // bf16 [6][S][S]
constexpr size_t CX_OFF    = RB_OFF + 6ull * NS * NS * 2;         // f32 [6][S]
constexpr size_t POTX_OFF  = CX_OFF + 6ull * NS * 4;              // f32 [6][B][S]
constexpr size_t POTY_OFF  = POTX_OFF + 6ull * NB * NS * 4;       // f32 [6][B][S]  (zeroed)
constexpr size_t CY_OFF    = POTY_OFF + 6ull * NB * NS * 4;       // f32 [6][S]

// ================= embed kernel =================
// job = u*5 + m;  m: 0=unary, 1=sp_x, 2=sp_y, 3/4 = pair-side embeds of util u.
// Block: 64 positions x 128 outputs, K=128, 4 waves (2 pos-halves x 2 out-halves).
__global__ __launch_bounds__(256, 2) void embed_kernel(
    const float* __restrict__ utils,
    const float* __restrict__ un_w1, const float* __restrict__ un_b1,
    const float* __restrict__ un_w2, const float* __restrict__ un_b2,
    const float* __restrict__ sp_wx, const float* __restrict__ sp_bx,
    const float* __restrict__ sp_wy, const float* __restrict__ sp_by,
    const float* __restrict__ pw_wx, const float* __restrict__ pw_bx,
    const float* __restrict__ pw_wy, const float* __restrict__ pw_by,
    unsigned short* __restrict__ emb, float* __restrict__ unp)
{
  const int job = blockIdx.x >> 9;
  const int pt  = blockIdx.x & 511;
  const int u = job / 5, m = job % 5;

  const float* W; const float* bias;
  unsigned short* dst = nullptr;
  int mode;
  if (m == 0)      { W = un_w1 + u*EE*EE; bias = un_b1 + u*EE; mode = 0; }
  else if (m == 1) { W = sp_wx + u*EE*EE; bias = sp_bx + u*EE; dst = emb + (size_t)(2*u)*BSE;   mode = 1; }
  else if (m == 2) { W = sp_wy + u*EE*EE; bias = sp_by + u*EE; dst = emb + (size_t)(2*u+1)*BSE; mode = 1; }
  else {
    int q, side;
    if (u == 0)      { q = (m == 3) ? 0 : 1; side = 0; }
    else if (u == 1) { if (m == 3) { q = 0; side = 1; } else { q = 2; side = 0; } }
    else             { q = (m == 3) ? 1 : 2; side = 1; }
    W    = (side == 0 ? pw_wx : pw_wy) + q*EE*EE;
    bias = (side == 0 ? pw_bx : pw_by) + q*EE;
    dst  = emb + (size_t)(2*(3+q)+side)*BSE;
    mode = 1;
  }

  __shared__ short lA[64*128];
  __shared__ short lB[128*128];
  __shared__ float redbuf[64];

  const int t = threadIdx.x;
  {
    const char* src = (const char*)(utils + (size_t)u*BSE + (size_t)pt*64*EE);
#pragma unroll
    for (int c = 0; c < 8; ++c) {
      int off = c*4096 + t*16;
      float4 v = *(const float4*)(src + off);
      s16x4 h;
      h.x = (short)f2bf(v.x); h.y = (short)f2bf(v.y);
      h.z = (short)f2bf(v.z); h.w = (short)f2bf(v.w);
      *(s16x4*)((char*)lA + swz(off >> 1)) = h;
    }
    const char* wsrc = (const char*)W;
#pragma unroll
    for (int c = 0; c < 16; ++c) {
      int off = c*4096 + t*16;
      float4 v = *(const float4*)(wsrc + off);
      s16x4 h;
      h.x = (short)f2bf(v.x); h.y = (short)f2bf(v.y);
      h.z = (short)f2bf(v.z); h.w = (short)f2bf(v.w);
      *(s16x4*)((char*)lB + swz(off >> 1)) = h;
    }
  }
  __syncthreads();

  const int lane = t & 63, wv = t >> 6;
  const int wrE = wv & 1, wcE = wv >> 1;
  const int cL = lane & 15, r4 = (lane >> 4) * 4, k8 = (lane >> 4) * 8;

  f32x4 acc[2][4];
#pragma unroll
  for (int i = 0; i < 2; ++i)
#pragma unroll
    for (int j = 0; j < 4; ++j) acc[i][j] = f32x4{0.f, 0.f, 0.f, 0.f};

#pragma unroll
  for (int kk = 0; kk < 4; ++kk) {
    s16x8 av[2], bv[4];
#pragma unroll
    for (int i = 0; i < 2; ++i) {
      int row = wrE*32 + i*16 + cL;
      av[i] = *(const s16x8*)((const char*)lA + swz(row*256 + kk*64 + k8*2));
    }
#pragma unroll
    for (int j = 0; j < 4; ++j) {
      int row = wcE*64 + j*16 + cL;
      bv[j] = *(const s16x8*)((const char*)lB + swz(row*256 + kk*64 + k8*2));
    }
#pragma unroll
    for (int i = 0; i < 2; ++i)
#pragma unroll
      for (int j = 0; j < 4; ++j)
        acc[i][j] = mfma16(av[i], bv[j], acc[i][j]);
  }

  if (mode == 0) {
    const float* w2 = un_w2 + u*EE;
    float s[2][4];
#pragma unroll
    for (int i = 0; i < 2; ++i)
#pragma unroll
      for (int r = 0; r < 4; ++r) s[i][r] = 0.f;
#pragma unroll
    for (int i = 0; i < 2; ++i) {
#pragma unroll
      for (int j = 0; j < 4; ++j) {
        int o = wcE*64 + j*16 + cL;
        float bv2 = bias[o], w2v = w2[o];
#pragma unroll
        for (int r = 0; r < 4; ++r) {
          float v = acc[i][j][r] + bv2;
          v = v > 0.f ? v : 0.f;
          s[i][r] += v * w2v;
        }
      }
    }
#pragma unroll
    for (int msk = 1; msk < 16; msk <<= 1)
#pragma unroll
      for (int i = 0; i < 2; ++i)
#pragma unroll
        for (int r = 0; r < 4; ++r)
          s[i][r] += __shfl_xor(s[i][r], msk, 64);
    if (t < 64) redbuf[t] = 0.f;
    __syncthreads();
    if (cL == 0) {
#pragma unroll
      for (int i = 0; i < 2; ++i)
#pragma unroll
        for (int r = 0; r < 4; ++r)
          atomicAdd(&redbuf[wrE*32 + i*16 + r4 + r], s[i][r]);
    }
    __syncthreads();
    if (t < 64) unp[(size_t)u*NB*NS + (size_t)pt*64 + t] = redbuf[t] + un_b2[u];
  } else {
    float nrm[2][4];
#pragma unroll
    for (int i = 0; i < 2; ++i)
#pragma unroll
      for (int r = 0; r < 4; ++r) nrm[i][r] = 0.f;
#pragma unroll
    for (int i = 0; i < 2; ++i) {
#pragma unroll
      for (int j = 0; j < 4; ++j) {
        int o = wcE*64 + j*16 + cL;
        float bv2 = bias[o];
#pragma unroll
        for (int r = 0; r < 4; ++r) {
          acc[i][j][r] += bv2;
          nrm[i][r] += acc[i][j][r] * acc[i][j][r];
        }
      }
    }
#pragma unroll
    for (int msk = 1; msk < 16; msk <<= 1)
#pragma unroll
      for (int i = 0; i < 2; ++i)
#pragma unroll
        for (int r = 0; r < 4; ++r)
          nrm[i][r] += __shfl_xor(nrm[i][r], msk, 64);
    if (t < 64) redbuf[t] = 0.f;
    __syncthreads();
    if (cL == 0) {
#pragma unroll
      for (int i = 0; i < 2; ++i)
#pragma unroll
        for (int r = 0; r < 4; ++r)
          atomicAdd(&redbuf[wrE*32 + i*16 + r4 + r], nrm[i][r]);
    }
    __syncthreads();
#pragma unroll
    for (int i = 0; i < 2; ++i) {
#pragma unroll
      for (int r = 0; r < 4; ++r) {
        float n = redbuf[wrE*32 + i*16 + r4 + r];
        float sc = 1.f / fmaxf(sqrtf(n), 1e-12f);
        size_t pbase = ((size_t)pt*64 + wrE*32 + i*16 + r4 + r) * EE;
#pragma unroll
        for (int j = 0; j < 4; ++j) {
          int o = wcE*64 + j*16 + cL;
          dst[pbase + o] = f2bf(acc[i][j][r] * sc);
        }
      }
    }
  }
}

// ================= pass 1: batch stats of S =================
// Block = (p, xt, yt): 128x128 tile. Loop b: MFMA S-tile, accumulate sum / sum^2.
__global__ __launch_bounds__(256, 1) void pass1_kernel(
    const unsigned short* __restrict__ emb,
    float* __restrict__ sumS, float* __restrict__ sumS2)
{
  const int bid = blockIdx.x;
  const int p = bid >> 6, xt = (bid >> 3) & 7, yt = bid & 7;
  const char* Xe = (const char*)(emb + (size_t)(2*p)*BSE + (size_t)xt*128*EE);
  const char* Ye = (const char*)(emb + (size_t)(2*p+1)*BSE + (size_t)yt*128*EE);
  __shared__ short lA[128*128];
  __shared__ short lB[128*128];
  const int t = threadIdx.x, lane = t & 63, wv = t >> 6;
  const int wr = wv >> 1, wc = wv & 1, cL = lane & 15, r4 = (lane >> 4) * 4, k8 = (lane >> 4) * 8;

  f32x4 sS[4][4], sQ[4][4];
#pragma unroll
  for (int i = 0; i < 4; ++i)
#pragma unroll
    for (int j = 0; j < 4; ++j) { sS[i][j] = f32x4{0.f,0.f,0.f,0.f}; sQ[i][j] = f32x4{0.f,0.f,0.f,0.f}; }

  for (int b = 0; b < NB; ++b) {
    __syncthreads();
    const char* Ab = Xe + (size_t)b * NS * EE * 2;
    const char* Bb = Ye + (size_t)b * NS * EE * 2;
#pragma unroll
    for (int c = 0; c < 8; ++c) {
      int off = c*4096 + t*16;
      int so = swz(off);
      *(s16x8*)((char*)lA + so) = *(const s16x8*)(Ab + off);
      *(s16x8*)((char*)lB + so) = *(const s16x8*)(Bb + off);
    }
    __syncthreads();
    f32x4 acc[4][4];
#pragma unroll
    for (int i = 0; i < 4; ++i)
#pragma unroll
      for (int j = 0; j < 4; ++j) acc[i][j] = f32x4{0.f,0.f,0.f,0.f};
#pragma unroll
    for (int kk = 0; kk < 4; ++kk) {
      s16x8 av[4], bv[4];
#pragma unroll
      for (int i = 0; i < 4; ++i) {
        int row = wr*64 + i*16 + cL;
        av[i] = *(const s16x8*)((const char*)lA + swz(row*256 + kk*64 + k8*2));
      }
#pragma unroll
      for (int j = 0; j < 4; ++j) {
        int row = wc*64 + j*16 + cL;
        bv[j] = *(const s16x8*)((const char*)lB + swz(row*256 + kk*64 + k8*2));
      }
#pragma unroll
      for (int i = 0; i < 4; ++i)
#pragma unroll
        for (int j = 0; j < 4; ++j)
          acc[i][j] = mfma16(av[i], bv[j], acc[i][j]);
    }
#pragma unroll
    for (int i = 0; i < 4; ++i)
#pragma unroll
      for (int j = 0; j < 4; ++j) {
        sS[i][j] += acc[i][j];
        sQ[i][j] += acc[i][j] * acc[i][j];
      }
  }
  float* oS = sumS  + (size_t)p * NS * NS;
  float* oQ = sumS2 + (size_t)p * NS * NS;
#pragma unroll
  for (int i = 0; i < 4; ++i)
#pragma unroll
    for (int j = 0; j < 4; ++j)
#pragma unroll
      for (int r = 0; r < 4; ++r) {
        int row = xt*128 + wr*64 + i*16 + r4 + r;
        int col = yt*128 + wc*64 + j*16 + cL;
        oS[(size_t)row*NS + col] = sS[i][j][r];
        oQ[(size_t)row*NS + col] = sQ[i][j][r];
      }
}

// ================= stats: rstd -> R(bf16), cX row-reduction (no atomics) =================
__global__ void stats_kernel(
    const float* __restrict__ sumS, const float* __restrict__ sumS2,
    const float* __restrict__ sp_g, const float* __restrict__ sp_b,
    const float* __restrict__ sp_mxw, const float* __restrict__ sp_mxb,
    const float* __restrict__ pw_g, const float* __restrict__ pw_b,
    const float* __restrict__ pw_mxw, const float* __restrict__ pw_mxb,
    unsigned short* __restrict__ Rb, float* __restrict__ cX)
{
  const int p = blockIdx.x >> 10, x = blockIdx.x & 1023, t = threadIdx.x;
  const float* g; const float* bb; const float* mxw; float mxb;
  if (p < 3) {
    g = sp_g + (size_t)p*NS*NS; bb = sp_b + (size_t)p*NS*NS;
    mxw = sp_mxw + p*NS; mxb = sp_mxb[p];
  } else {
    int q = p - 3;
    g = pw_g + (size_t)q*NS*NS; bb = pw_b + (size_t)q*NS*NS;
    mxw = pw_mxw + q*NS; mxb = pw_mxb[q];
  }
  const size_t ro = (size_t)p*NS*NS + (size_t)x*NS;
  const size_t gro = (size_t)x*NS;
  const int y = t * 4;
  float4 s4 = *(const float4*)(sumS + ro + y);
  float4 q4 = *(const float4*)(sumS2 + ro + y);
  float4 g4 = *(const float4*)(g + gro + y);
  float4 b4 = *(const float4*)(bb + gro + y);
  float4 m4 = *(const float4*)(mxw + y);
  float partial = 0.f;
  s16x4 rq;
  {
    const float inv = 1.f / 32.f;
    float sv[4] = {s4.x, s4.y, s4.z, s4.w};
    float qv[4] = {q4.x, q4.y, q4.z, q4.w};
    float gv[4] = {g4.x, g4.y, g4.z, g4.w};
    float bv[4] = {b4.x, b4.y, b4.z, b4.w};
    float mw[4] = {m4.x, m4.y, m4.z, m4.w};
#pragma unroll
    for (int c = 0; c < 4; ++c) {
      float mean = sv[c] * inv;
      float var  = qv[c] * inv - mean * mean;
      float rstd = rsqrtf(var + 1e-5f);
      unsigned short rh = f2bf(gv[c] * rstd);
      rq[c] = (short)rh;
      float Rq = bf2f(rh);
      partial += mw[c] * (bv[c] - Rq * mean);
    }
  }
  *(s16x4*)(Rb + ro + y) = rq;
  __shared__ float sred[256];
  sred[t] = partial;
  __syncthreads();
  if (t < 128) sred[t] += sred[t + 128];
  __syncthreads();
  if (t < 64) {
    float v = sred[t] + sred[t + 64];
#pragma unroll
    for (int msk = 1; msk < 64; msk <<= 1) v += __shfl_xor(v, msk, 64);
    if (t == 0) cX[p*NS + x] = v + mxb;
  }
}

// ================= cY: column reduction, exclusive writes (replaces atomics) =================
// Block = (q, 64-col strip). 4 row-groups x 64 lanes; coalesced 256B rows.
__global__ __launch_bounds__(256, 4) void cy_kernel(
    const float* __restrict__ sumS, const unsigned short* __restrict__ Rb,
    const float* __restrict__ pw_b, const float* __restrict__ pw_myw,
    float* __restrict__ cY)
{
  const int q = blockIdx.x >> 4, ys = blockIdx.x & 15;
  const int p = q + 3;
  const int t = threadIdx.x, rg = t >> 6, c = t & 63;
  const int y = ys * 64 + c;
  const float* Sp = sumS + (size_t)p * NS * NS;
  const unsigned short* Rp = Rb + (size_t)p * NS * NS;
  const float* bbp = pw_b + (size_t)q * NS * NS;
  const float* myw = pw_myw + q * NS;
  const float inv = 1.f / 32.f;
  float acc = 0.f;
#pragma unroll 4
  for (int x = rg * 256; x < rg * 256 + 256; ++x) {
    float mw = myw[x];
    float mean = Sp[(size_t)x * NS + y] * inv;
    float R = bf2f(Rp[(size_t)x * NS + y]);
    float bbv = bbp[(size_t)x * NS + y];
    acc += mw * (bbv - R * mean);
  }
  __shared__ float red[256];
  red[t] = acc;
  __syncthreads();
  if (rg == 0)
    cY[(size_t)p * NS + y] = red[c] + red[64 + c] + red[128 + c] + red[192 + c];
}

// ================= pass 2: recompute S, weighted reductions =================
// Block = (p, b, xt). Loops yt. potX exclusive per block; potY via atomics.
__global__ __launch_bounds__(256, 2) void pass2_kernel(
    const unsigned short* __restrict__ emb, const unsigned short* __restrict__ Rb,
    const float* __restrict__ sp_mxw, const float* __restrict__ pw_mxw,
    const float* __restrict__ pw_myw,
    float* __restrict__ potX, float* __restrict__ potY)
{
  const int bid = blockIdx.x;
  const int p = bid >> 8, b = (bid >> 3) & 31, xt = bid & 7;
  const char* Ae = (const char*)(emb + (size_t)(2*p)*BSE + ((size_t)b*NS + (size_t)xt*128)*EE);
  const char* Be = (const char*)(emb + (size_t)(2*p+1)*BSE + (size_t)b*NS*EE);
  const unsigned short* Rp = Rb + (size_t)p*NS*NS;
  const float* mxw = (p < 3) ? (sp_mxw + p*NS) : (pw_mxw + (p-3)*NS);
  const float* myw = (p < 3) ? nullptr : (pw_myw + (p-3)*NS);
  __shared__ short lA[128*128];
  __shared__ short lB[128*128];
  __shared__ float pxbuf[128];
  const int t = threadIdx.x, lane = t & 63, wv = t >> 6;
  const int wr = wv >> 1, wc = wv & 1, cL = lane & 15, r4 = (lane >> 4) * 4, k8 = (lane >> 4) * 8;

#pragma unroll
  for (int c = 0; c < 8; ++c) {
    int off = c*4096 + t*16;
    *(s16x8*)((char*)lA + swz(off)) = *(const s16x8*)(Ae + off);
  }
  float px[4][4];
#pragma unroll
  for (int i = 0; i < 4; ++i)
#pragma unroll
    for (int r = 0; r < 4; ++r) px[i][r] = 0.f;
  float mywv[4][4];
  if (myw) {
#pragma unroll
    for (int i = 0; i < 4; ++i)
#pragma unroll
      for (int r = 0; r < 4; ++r)
        mywv[i][r] = myw[xt*128 + wr*64 + i*16 + r4 + r];
  }

  for (int yt = 0; yt < 8; ++yt) {
    __syncthreads();
#pragma unroll
    for (int c = 0; c < 8; ++c) {
      int off = c*4096 + t*16;
      *(s16x8*)((char*)lB + swz(off)) = *(const s16x8*)(Be + (size_t)yt*32768 + off);
    }
    __syncthreads();
    f32x4 acc[4][4];
#pragma unroll
    for (int i = 0; i < 4; ++i)
#pragma unroll
      for (int j = 0; j < 4; ++j) acc[i][j] = f32x4{0.f,0.f,0.f,0.f};
#pragma unroll
    for (int kk = 0; kk < 4; ++kk) {
      s16x8 av[4], bv[4];
#pragma unroll
      for (int i = 0; i < 4; ++i) {
        int row = wr*64 + i*16 + cL;
        av[i] = *(const s16x8*)((const char*)lA + swz(row*256 + kk*64 + k8*2));
      }
#pragma unroll
      for (int j = 0; j < 4; ++j) {
        int row = wc*64 + j*16 + cL;
        bv[j] = *(const s16x8*)((const char*)lB + swz(row*256 + kk*64 + k8*2));
      }
#pragma unroll
      for (int i = 0; i < 4; ++i)
#pragma unroll
        for (int j = 0; j < 4; ++j)
          acc[i][j] = mfma16(av[i], bv[j], acc[i][j]);
    }
    float mxl[4];
#pragma unroll
    for (int j = 0; j < 4; ++j) mxl[j] = mxw[yt*128 + wc*64 + j*16 + cL];

    if (myw) {
      float py[4] = {0.f, 0.f, 0.f, 0.f};
#pragma unroll
      for (int i = 0; i < 4; ++i) {
#pragma unroll
        for (int r = 0; r < 4; ++r) {
          const unsigned short* Rr = Rp + (size_t)(xt*128 + wr*64 + i*16 + r4 + r)*NS + yt*128;
          float pxa = 0.f;
#pragma unroll
          for (int j = 0; j < 4; ++j) {
            float Rv = bf2f(Rr[wc*64 + j*16 + cL]);
            float tt = Rv * acc[i][j][r];
            pxa += mxl[j] * tt;
            py[j] += mywv[i][r] * tt;
          }
          px[i][r] += pxa;
        }
      }
#pragma unroll
      for (int j = 0; j < 4; ++j) {
        py[j] += __shfl_xor(py[j], 16, 64);
        py[j] += __shfl_xor(py[j], 32, 64);
      }
      if ((lane >> 4) == 0) {
#pragma unroll
        for (int j = 0; j < 4; ++j)
          atomicAdd(&potY[((size_t)p*NB + b)*NS + yt*128 + wc*64 + j*16 + cL], py[j]);
      }
    } else {
#pragma unroll
      for (int i = 0; i < 4; ++i) {
#pragma unroll
        for (int r = 0; r < 4; ++r) {
          const unsigned short* Rr = Rp + (size_t)(xt*128 + wr*64 + i*16 + r4 + r)*NS + yt*128;
          float pxa = 0.f;
#pragma unroll
          for (int j = 0; j < 4; ++j) {
            float Rv = bf2f(Rr[wc*64 + j*16 + cL]);
            pxa += mxl[j] * (Rv * acc[i][j][r]);
          }
          px[i][r] += pxa;
        }
      }
    }
  }
#pragma unroll
  for (int msk = 1; msk < 16; msk <<= 1)
#pragma unroll
    for (int i = 0; i < 4; ++i)
#pragma unroll
      for (int r = 0; r < 4; ++r)
        px[i][r] += __shfl_xor(px[i][r], msk, 64);
  if (t < 128) pxbuf[t] = 0.f;
  __syncthreads();
  if (cL == 0) {
#pragma unroll
    for (int i = 0; i < 4; ++i)
#pragma unroll
      for (int r = 0; r < 4; ++r)
        atomicAdd(&pxbuf[wr*64 + i*16 + r4 + r], px[i][r]);
  }
  __syncthreads();
  if (t < 128) potX[((size_t)p*NB + b)*NS + (size_t)xt*128 + t] = pxbuf[t];
}

// ================= final: red -> softmax -> weighted sum of utils =================
__global__ __launch_bounds__(256, 4) void final_kernel(
    const float* __restrict__ utils, const float* __restrict__ unp,
    const float* __restrict__ potX, const float* __restrict__ potY,
    const float* __restrict__ cX, const float* __restrict__ cY,
    const float* __restrict__ pw_myb, const float* __restrict__ red_w,
    float* __restrict__ out)
{
  const int u = blockIdx.x >> 5, b = blockIdx.x & 31, t = threadIdx.x;
  const int lane = t & 63, wv = t >> 6;
  __shared__ float wts[1024];
  __shared__ float redA[4], redB[4];
  __shared__ float comb[128];
  const float* unpp  = unp  + ((size_t)u*NB + b)*NS;
  const float* selfX = potX + ((size_t)u*NB + b)*NS;
  const float* cXu   = cX + u*NS;
  const float rw0 = red_w[u*4+0], rw1 = red_w[u*4+1], rw2 = red_w[u*4+2], rw3 = red_w[u*4+3];
  const float *p2, *p3, *c2, *c3; float a2, a3;
  if (u == 0) {
    p2 = potX + ((size_t)3*NB + b)*NS; c2 = cX + 3*NS; a2 = 0.f;
    p3 = potX + ((size_t)4*NB + b)*NS; c3 = cX + 4*NS; a3 = 0.f;
  } else if (u == 1) {
    p2 = potY + ((size_t)3*NB + b)*NS; c2 = cY + 3*NS; a2 = pw_myb[0];
    p3 = potX + ((size_t)5*NB + b)*NS; c3 = cX + 5*NS; a3 = 0.f;
  } else {
    p2 = potY + ((size_t)4*NB + b)*NS; c2 = cY + 4*NS; a2 = pw_myb[1];
    p3 = potY + ((size_t)5*NB + b)*NS; c3 = cY + 5*NS; a3 = pw_myb[2];
  }
  float rv[4]; float lmax = -3.4e38f;
#pragma unroll
  for (int k = 0; k < 4; ++k) {
    int s = t*4 + k;
    float v = rw0*unpp[s] + rw1*(selfX[s] + cXu[s])
            + rw2*(p2[s] + c2[s] + a2) + rw3*(p3[s] + c3[s] + a3);
    rv[k] = v; lmax = fmaxf(lmax, v);
  }
#pragma unroll
  for (int msk = 1; msk < 64; msk <<= 1) lmax = fmaxf(lmax, __shfl_xor(lmax, msk, 64));
  if (lane == 0) redA[wv] = lmax;
  __syncthreads();
  const float gmax = fmaxf(fmaxf(redA[0], redA[1]), fmaxf(redA[2], redA[3]));
  float lsum = 0.f;
#pragma unroll
  for (int k = 0; k < 4; ++k) {
    float e2 = __expf(rv[k] - gmax);
    wts[t*4 + k] = e2; lsum += e2;
  }
#pragma unroll
  for (int msk = 1; msk < 64; msk <<= 1) lsum += __shfl_xor(lsum, msk, 64);
  if (lane == 0) redB[wv] = lsum;
  __syncthreads();
  const float inv = 1.f / (redB[0] + redB[1] + redB[2] + redB[3]);
  const int e = t & 127, half = t >> 7;
  const float* ub = utils + (size_t)u*BSE + (size_t)b*NS*EE;
  float acc = 0.f;
  const int s0 = half * 512;
#pragma unroll 8
  for (int s = s0; s < s0 + 512; ++s)
    acc += ub[(size_t)s*EE + e] * wts[s];
  if (half) comb[e] = acc;
  __syncthreads();
  if (!half) out[((size_t)u*NB + b)*EE + e] = (acc + comb[e]) * inv;
}

// ================= host launch =================
extern "C" void kernel_launch(void* const* d_in, const int* in_sizes, int n_in,
                              void* d_out, int out_size, void* d_ws, size_t ws_size,
                              hipStream_t stream)
{
  (void)in_sizes; (void)n_in; (void)out_size; (void)ws_size;
  const float* utils  = (const float*)d_in[0];
  const float* un_w1  = (const float*)d_in[1];
  const float* un_b1  = (const float*)d_in[2];
  const float* un_w2  = (const float*)d_in[3];
  const float* un_b2  = (const float*)d_in[4];
  const float* sp_wx  = (const float*)d_in[5];
  const float* sp_bx  = (const float*)d_in[6];
  const float* sp_wy  = (const float*)d_in[7];
  const float* sp_by  = (const float*)d_in[8];
  const float* sp_g   = (const float*)d_in[9];
  const float* sp_b   = (const float*)d_in[10];
  const float* sp_mxw = (const float*)d_in[11];
  const float* sp_mxb = (const float*)d_in[12];
  const float* pw_wx  = (const float*)d_in[13];
  const float* pw_bx  = (const float*)d_in[14];
  const float* pw_wy  = (const float*)d_in[15];
  const float* pw_by  = (const float*)d_in[16];
  const float* pw_g   = (const float*)d_in[17];
  const float* pw_b   = (const float*)d_in[18];
  const float* pw_mxw = (const float*)d_in[19];
  const float* pw_mxb = (const float*)d_in[20];
  const float* pw_myw = (const float*)d_in[21];
  const float* pw_myb = (const float*)d_in[22];
  const float* red_w  = (const float*)d_in[23];
  float* out = (float*)d_out;
  char* ws = (char*)d_ws;

  unsigned short* embp  = (unsigned short*)(ws + EMB_OFF);
  float* unpp           = (float*)(ws + UNP_OFF);
  float* sumSp          = (float*)(ws + SUMS_OFF);
  float* sumS2p         = (float*)(ws + SUMS2_OFF);
  unsigned short* Rbp   = (unsigned short*)(ws + RB_OFF);
  float* cXp            = (float*)(ws + CX_OFF);
  float* potXp          = (float*)(ws + POTX_OFF);
  float* potYp          = (float*)(ws + POTY_OFF);
  float* cYp            = (float*)(ws + CY_OFF);

  hipMemsetAsync(ws + POTY_OFF, 0, 6ull*NB*NS*4, stream);

  embed_kernel<<<dim3(7680), dim3(256), 0, stream>>>(
      utils, un_w1, un_b1, un_w2, un_b2, sp_wx, sp_bx, sp_wy, sp_by,
      pw_wx, pw_bx, pw_wy, pw_by, embp, unpp);
  pass1_kernel<<<dim3(384), dim3(256), 0, stream>>>(embp, sumSp, sumS2p);
  stats_kernel<<<dim3(6144), dim3(256), 0, stream>>>(
      sumSp, sumS2p, sp_g, sp_b, sp_mxw, sp_mxb,
      pw_g, pw_b, pw_mxw, pw_mxb, Rbp, cXp);
  cy_kernel<<<dim3(48), dim3(256), 0, stream>>>(
      sumSp, Rbp, pw_b, pw_myw, cYp);
  pass2_kernel<<<dim3(1536), dim3(256), 0, stream>>>(
      embp, Rbp, sp_mxw, pw_mxw, pw_myw, potXp, potYp);
  final_kernel<<<dim3(96), dim3(256), 0, stream>>>(
      utils, unpp, potXp, potYp, cXp, cYp, pw_myb, red_w, out);
}